// Round 9
// baseline (819.535 us; speedup 1.0000x reference)
//
#include <hip/hip_runtime.h>
#include <hip/hip_fp16.h>

#define N_NODES 100000
#define EMB_DIM 64
#define N_EDGES 3200000
#define N_LAYERS 3

#define SCAN_BLOCK 512
#define N_SCAN_BLOCKS ((N_NODES + SCAN_BLOCK - 1) / SCAN_BLOCK)   // 196

// Coarse bins for the two-phase CSR build.
#define ABINROWS 256
#define NBINS ((N_NODES + ABINROWS - 1) / ABINROWS)   // 391
#define NBINS_P 512
#define ACHUNK 2048
#define AEPT 8
#define NCHUNKS ((N_EDGES + ACHUNK - 1) / ACHUNK)     // 1563
#define BCHUNK 4096
#define NBCHUNKS ((N_EDGES + BCHUNK - 1) / BCHUNK)    // 782

// Column partition: 4 parts x 25000 source rows = 3.2 MB bf16 mirror slice,
// fits one XCD's 4 MB L2. Pass p (one dispatch) touches only part p.
#define NPART 4
#define PART_DIV 25000

// d_out layout: mean [N_NODES*64] first, then stacked [N_NODES*4*64]
// stacked[n][l][d] at n*256 + l*64 + d

typedef float f32x4 __attribute__((ext_vector_type(4)));
typedef unsigned short u16x4 __attribute__((ext_vector_type(4)));

__device__ __forceinline__ unsigned short f32_to_bf16_rtn(float f) {
    unsigned u = __float_as_uint(f);
    unsigned r = u + 0x7FFFu + ((u >> 16) & 1u);
    return (unsigned short)(r >> 16);
}
__device__ __forceinline__ float bf16_to_f32(unsigned short h) {
    return __uint_as_float(((unsigned)h) << 16);
}

// ---------- bin-level counting ----------

__global__ void __launch_bounds__(256) bin_count(const int* __restrict__ rows,
                                                 int* __restrict__ binCounts) {
    __shared__ int h[NBINS];
    int t = threadIdx.x;
    for (int i = t; i < NBINS; i += 256) h[i] = 0;
    __syncthreads();
    int base = blockIdx.x * BCHUNK;
    int n = N_EDGES - base; if (n > BCHUNK) n = BCHUNK;
    for (int i = t; i < n; i += 256)
        atomicAdd(&h[__builtin_nontemporal_load(rows + base + i) >> 8], 1);
    __syncthreads();
    for (int i = t; i < NBINS; i += 256) {
        int c = h[i];
        if (c) atomicAdd(&binCounts[i], c);
    }
}

__global__ void __launch_bounds__(512) bin_scan(const int* __restrict__ binCounts,
                                                int* __restrict__ binPtr) {
    __shared__ int sm[512];
    int t = threadIdx.x;
    int v = (t < NBINS) ? binCounts[t] : 0;
    sm[t] = v;
    __syncthreads();
    for (int off = 1; off < 512; off <<= 1) {
        int u = (t >= off) ? sm[t - off] : 0;
        __syncthreads();
        sm[t] += u;
        __syncthreads();
    }
    if (t < NBINS) binPtr[t + 1] = sm[t];
    if (t == 0) binPtr[0] = 0;
}

// ---------- legacy per-row count + scan (f32 fallback path only) ----------

__global__ void count_rows(const int* __restrict__ rows, int* __restrict__ counts) {
    int e = blockIdx.x * blockDim.x + threadIdx.x;
    if (e >= N_EDGES) return;
    atomicAdd(&counts[rows[e]], 1);
}

__global__ void __launch_bounds__(SCAN_BLOCK) scan_phase1(const int* __restrict__ counts,
                                                          int* __restrict__ blockSums) {
    __shared__ int sm[SCAN_BLOCK];
    int idx = blockIdx.x * SCAN_BLOCK + threadIdx.x;
    int v = (idx < N_NODES) ? counts[idx] : 0;
    sm[threadIdx.x] = v;
    __syncthreads();
    for (int off = SCAN_BLOCK / 2; off > 0; off >>= 1) {
        if (threadIdx.x < off) sm[threadIdx.x] += sm[threadIdx.x + off];
        __syncthreads();
    }
    if (threadIdx.x == 0) blockSums[blockIdx.x] = sm[0];
}

__global__ void __launch_bounds__(256) scan_phase2(const int* __restrict__ blockSums,
                                                   int* __restrict__ blockOffs,
                                                   int* __restrict__ row_ptr) {
    __shared__ int sm[256];
    int t = threadIdx.x;
    int v = (t < N_SCAN_BLOCKS) ? blockSums[t] : 0;
    sm[t] = v;
    __syncthreads();
    for (int off = 1; off < 256; off <<= 1) {
        int u = (t >= off) ? sm[t - off] : 0;
        __syncthreads();
        sm[t] += u;
        __syncthreads();
    }
    if (t < N_SCAN_BLOCKS) blockOffs[t] = (t == 0) ? 0 : sm[t - 1];
    if (t == 255) row_ptr[N_NODES] = sm[255];
}

__global__ void __launch_bounds__(SCAN_BLOCK) scan_phase3(const int* __restrict__ counts,
                                                          const int* __restrict__ blockOffs,
                                                          int* __restrict__ row_ptr) {
    __shared__ int sm[SCAN_BLOCK];
    int idx = blockIdx.x * SCAN_BLOCK + threadIdx.x;
    int t = threadIdx.x;
    int v = (idx < N_NODES) ? counts[idx] : 0;
    sm[t] = v;
    __syncthreads();
    for (int off = 1; off < SCAN_BLOCK; off <<= 1) {
        int u = (t >= off) ? sm[t - off] : 0;
        __syncthreads();
        sm[t] += u;
        __syncthreads();
    }
    if (idx < N_NODES) row_ptr[idx] = blockOffs[blockIdx.x] + sm[t] - v;
}

// ---------- phase A: LDS counting-sort partition by bin (dense run writes) ----------
// Packed edge: col (17 bits) << 15 | fp16(val) low 15 bits (val>=0 so sign=0).

__global__ void __launch_bounds__(256) build_sortA(const int* __restrict__ rows,
                                                   const int* __restrict__ cols,
                                                   const float* __restrict__ vals,
                                                   const int* __restrict__ binPtr,
                                                   int* __restrict__ bucketFill,
                                                   uint2* __restrict__ records) {
    __shared__ int binCnt[NBINS_P];
    __shared__ int binInc[NBINS_P];   // inclusive prefix of binCnt
    __shared__ int binCur[NBINS_P];
    __shared__ int binG[NBINS];       // global dst base of this WG's run per bin
    __shared__ uint2 buf[ACHUNK];     // bin-sorted records

    int base = blockIdx.x * ACHUNK;
    int n = N_EDGES - base; if (n > ACHUNK) n = ACHUNK;
    int t = threadIdx.x;

    for (int i = t; i < NBINS_P; i += 256) { binCnt[i] = 0; binCur[i] = 0; }
    __syncthreads();

    // Load AEPT edges/thread (static unroll -> registers) + histogram.
    int r_[AEPT]; unsigned pk_[AEPT];
#pragma unroll AEPT
    for (int k = 0; k < AEPT; ++k) {
        int i = t + k * 256;
        r_[k] = 0; pk_[k] = 0;
        if (i < n) {
            int e = base + i;
            int r = __builtin_nontemporal_load(rows + e);
            unsigned hb = __half_as_ushort(__float2half(__builtin_nontemporal_load(vals + e)));
            r_[k] = r;
            pk_[k] = (((unsigned)__builtin_nontemporal_load(cols + e)) << 15) | (hb & 0x7FFFu);
            atomicAdd(&binCnt[r >> 8], 1);
        }
    }
    __syncthreads();

    // Hillis-Steele inclusive scan over NBINS_P entries (2 per thread).
    binInc[t] = binCnt[t];
    binInc[t + 256] = binCnt[t + 256];
    __syncthreads();
    for (int off = 1; off < NBINS_P; off <<= 1) {
        int i0 = t, i1 = t + 256;
        int v0 = (i0 >= off) ? binInc[i0 - off] : 0;
        int v1 = (i1 >= off) ? binInc[i1 - off] : 0;
        __syncthreads();
        binInc[i0] += v0;
        binInc[i1] += v1;
        __syncthreads();
    }

    // Scatter records into LDS at bin-sorted positions.
#pragma unroll AEPT
    for (int k = 0; k < AEPT; ++k) {
        int i = t + k * 256;
        if (i < n) {
            int b = r_[k] >> 8;
            int slot = (binInc[b] - binCnt[b]) + atomicAdd(&binCur[b], 1);
            buf[slot] = make_uint2((unsigned)r_[k], pk_[k]);
        }
    }
    // One global reservation per non-empty bin.
    for (int b = t; b < NBINS; b += 256) {
        int c = binCnt[b];
        if (c > 0) binG[b] = binPtr[b] + atomicAdd(&bucketFill[b], c);
    }
    __syncthreads();

    // Coalesced copy-out: consecutive p within a run -> consecutive global dst.
    for (int p = t; p < n; p += 256) {
        uint2 rec = buf[p];
        int b = (int)(rec.x >> 8);
        int dst = binG[b] + (p - (binInc[b] - binCnt[b]));
        records[dst] = rec;
    }
}

// ---------- phase B: per-(row,part) segment derivation + scatter ----------
// Counting-sort key = row*4 + col-part (1024 LDS counters, two-level scan).
// Emits rp2[4N+1]: segment pointers so pass p of the SpMM reads exactly the
// edges whose source column lies in mirror part p (3.2 MB, L2-resident).
__global__ void __launch_bounds__(256) build_phaseB(const int* __restrict__ binPtr,
                                                    const uint2* __restrict__ records,
                                                    unsigned* __restrict__ s_edges,
                                                    int* __restrict__ rp2) {
    __shared__ int lcnt[ABINROWS * NPART];
    __shared__ int lseg[ABINROWS * NPART];   // absolute segment starts
    __shared__ int lfill[ABINROWS * NPART];
    __shared__ int tot[256];
    int b = blockIdx.x;
    int t = threadIdx.x;
    int r0 = b * ABINROWS;
    int r1 = r0 + ABINROWS; if (r1 > N_NODES) r1 = N_NODES;
    int nr = r1 - r0;
    int beg = binPtr[b];
    int end = binPtr[b + 1];

    for (int i = t; i < ABINROWS * NPART; i += 256) { lcnt[i] = 0; lfill[i] = 0; }
    __syncthreads();
    // Pass 1: (row, part) histogram.
    for (int i = beg + t; i < end; i += 256) {
        uint2 rec = records[i];
        int p = (int)(rec.y >> 15) / PART_DIV;
        atomicAdd(&lcnt[((int)rec.x - r0) * NPART + p], 1);
    }
    __syncthreads();
    // Two-level exclusive scan of 1024 entries: thread t owns [4t..4t+3].
    int c0 = lcnt[4 * t + 0], c1 = lcnt[4 * t + 1], c2 = lcnt[4 * t + 2], c3 = lcnt[4 * t + 3];
    int lsum = c0 + c1 + c2 + c3;
    tot[t] = lsum;
    __syncthreads();
    for (int off = 1; off < 256; off <<= 1) {
        int u = (t >= off) ? tot[t - off] : 0;
        __syncthreads();
        tot[t] += u;
        __syncthreads();
    }
    int excl = tot[t] - lsum;
    lseg[4 * t + 0] = beg + excl;
    lseg[4 * t + 1] = beg + excl + c0;
    lseg[4 * t + 2] = beg + excl + c0 + c1;
    lseg[4 * t + 3] = beg + excl + c0 + c1 + c2;
    __syncthreads();
    // Dense rp2 write (seam value duplicated by neighbor bins is identical).
    for (int i = t; i < nr * NPART; i += 256) rp2[r0 * NPART + i] = lseg[i];
    if (b == NBINS - 1 && t == 0) rp2[N_NODES * NPART] = end;
    // Pass 2: scatter (records re-read is L2-resident).
    for (int i = beg + t; i < end; i += 256) {
        uint2 rec = records[i];
        int idx = ((int)rec.x - r0) * NPART + (int)(rec.y >> 15) / PART_DIV;
        int lp = atomicAdd(&lfill[idx], 1);
        s_edges[lseg[idx] + lp] = rec.y;
    }
}

// ---------- emb -> bf16 mirror (pure stream: nt both sides) ----------
__global__ void emb_to_bf16(const float* __restrict__ emb, unsigned short* __restrict__ mirror) {
    int t = blockIdx.x * blockDim.x + threadIdx.x;   // [0, N_NODES*16)
    if (t >= N_NODES * 16) return;
    f32x4 v = __builtin_nontemporal_load((const f32x4*)emb + t);
    u16x4 o;
    o.x = f32_to_bf16_rtn(v.x); o.y = f32_to_bf16_rtn(v.y);
    o.z = f32_to_bf16_rtn(v.z); o.w = f32_to_bf16_rtn(v.w);
    __builtin_nontemporal_store(o, (u16x4*)mirror + t);
}

// ---------- SpMM core (per-(row,part) segment) ----------
// 4 groups x 16 lanes; lane j of a group owns bf16x4 chunk j of the 64-dim row.
// Edge words staged via ONE coalesced per-lane load (nt: no reuse), distributed
// with __shfl. Mirror gathers cached (pass working set = 3.2 MB -> L2 hits).
// Control flow wave-uniform (shfl from inactive lanes undefined on CDNA).

__device__ __forceinline__ void gacc(float4& acc, unsigned p, int j,
                                     const unsigned short* __restrict__ srcMirror) {
    float v = __half2float(__ushort_as_half((unsigned short)(p & 0x7FFFu)));
    ushort4 m = *(const ushort4*)(srcMirror + (size_t)(p >> 15) * 64 + j * 4);
    acc.x += v * bf16_to_f32(m.x);
    acc.y += v * bf16_to_f32(m.y);
    acc.z += v * bf16_to_f32(m.z);
    acc.w += v * bf16_to_f32(m.w);
}

__device__ __forceinline__ float4 spmm_row_core(int beg, int end, int g, int j, int lane,
                                                const unsigned* __restrict__ s_edges,
                                                const unsigned short* __restrict__ srcMirror) {
    int deg = end - beg;                  // wave-uniform
    unsigned ew = (lane < deg) ? __builtin_nontemporal_load(s_edges + beg + lane) : 0u;
    float4 acc = make_float4(0.f, 0.f, 0.f, 0.f);
    int nfull = deg < 64 ? deg : 64;      // wave-uniform
    for (int kb = 0; kb < nfull; kb += 16) {
        int k0 = kb + g, k1 = kb + g + 4, k2 = kb + g + 8, k3 = kb + g + 12;
        unsigned p0 = __shfl(ew, k0);
        unsigned p1 = __shfl(ew, k1);
        unsigned p2 = __shfl(ew, k2);
        unsigned p3 = __shfl(ew, k3);
        if (k0 < nfull) gacc(acc, p0, j, srcMirror);
        if (k1 < nfull) gacc(acc, p1, j, srcMirror);
        if (k2 < nfull) gacc(acc, p2, j, srcMirror);
        if (k3 < nfull) gacc(acc, p3, j, srcMirror);
    }
    for (int e = beg + 64 + g; e < end; e += 4) {
        unsigned p = s_edges[e];
        gacc(acc, p, j, srcMirror);
    }
    acc.x += __shfl_xor(acc.x, 16); acc.y += __shfl_xor(acc.y, 16);
    acc.z += __shfl_xor(acc.z, 16); acc.w += __shfl_xor(acc.w, 16);
    acc.x += __shfl_xor(acc.x, 32); acc.y += __shfl_xor(acc.y, 32);
    acc.z += __shfl_xor(acc.z, 32); acc.w += __shfl_xor(acc.w, 32);
    return acc;
}

// One pass = one column part. accum: += into dst (f32 RMW across passes,
// serialized by dispatch boundaries). dstMirror written only on final pass.
__global__ void __launch_bounds__(256) spmm_pass(const int* __restrict__ rp2,
                                                 const unsigned* __restrict__ s_edges,
                                                 const unsigned short* __restrict__ srcMirror,
                                                 int p, int accum,
                                                 float* __restrict__ dst,
                                                 unsigned short* __restrict__ dstMirror) {
    int wave = (blockIdx.x * blockDim.x + threadIdx.x) >> 6;
    if (wave >= N_NODES) return;
    int lane = threadIdx.x & 63;
    int g = lane >> 4, j = lane & 15;
    int beg = rp2[wave * NPART + p];
    int end = rp2[wave * NPART + p + 1];
    float4 acc = spmm_row_core(beg, end, g, j, lane, s_edges, srcMirror);
    if (lane < 16) {
        float* out = dst + (size_t)wave * 256 + j * 4;
        if (accum) {
            f32x4 prev = __builtin_nontemporal_load((const f32x4*)out);
            acc.x += prev.x; acc.y += prev.y; acc.z += prev.z; acc.w += prev.w;
        }
        f32x4 vv = {acc.x, acc.y, acc.z, acc.w};
        __builtin_nontemporal_store(vv, (f32x4*)out);
        if (dstMirror) {
            u16x4 o;
            o.x = f32_to_bf16_rtn(acc.x); o.y = f32_to_bf16_rtn(acc.y);
            o.z = f32_to_bf16_rtn(acc.z); o.w = f32_to_bf16_rtn(acc.w);
            __builtin_nontemporal_store(o, (u16x4*)(dstMirror + (size_t)wave * 64 + j * 4));
        }
    }
}

// Final pass of the last layer: part 3 + layer-0 copy + layer-3 write + mean.
__global__ void __launch_bounds__(256) spmm_last_final(const int* __restrict__ rp2,
                                                       const unsigned* __restrict__ s_edges,
                                                       const unsigned short* __restrict__ srcMirror,
                                                       const float* __restrict__ emb,
                                                       float* __restrict__ stacked,
                                                       float* __restrict__ meanOut) {
    int wave = (blockIdx.x * blockDim.x + threadIdx.x) >> 6;
    if (wave >= N_NODES) return;
    int lane = threadIdx.x & 63;
    int g = lane >> 4, j = lane & 15;
    int beg = rp2[wave * NPART + 3];
    int end = rp2[wave * NPART + 4];
    float4 acc = spmm_row_core(beg, end, g, j, lane, s_edges, srcMirror);
    if (lane < 16) {
        float* base = stacked + (size_t)wave * 256 + j * 4;
        f32x4 prev = __builtin_nontemporal_load((const f32x4*)(base + 192));
        f32x4 d3 = {acc.x + prev.x, acc.y + prev.y, acc.z + prev.z, acc.w + prev.w};
        f32x4 a  = __builtin_nontemporal_load((const f32x4*)(emb + (size_t)wave * 64 + j * 4));
        f32x4 b1 = __builtin_nontemporal_load((const f32x4*)(base + 64));
        f32x4 c2 = __builtin_nontemporal_load((const f32x4*)(base + 128));
        __builtin_nontemporal_store(a, (f32x4*)base);            // layer 0
        __builtin_nontemporal_store(d3, (f32x4*)(base + 192));   // layer 3
        f32x4 s;
        s.x = 0.25f * (a.x + b1.x + c2.x + d3.x);
        s.y = 0.25f * (a.y + b1.y + c2.y + d3.y);
        s.z = 0.25f * (a.z + b1.z + c2.z + d3.z);
        s.w = 0.25f * (a.w + b1.w + c2.w + d3.w);
        __builtin_nontemporal_store(s, (f32x4*)(meanOut + (size_t)wave * 64 + j * 4));
    }
}

// ---------- mean over 4 layers (f32 fallback path) ----------
__global__ void mean_layers(const float* __restrict__ emb,
                            float* __restrict__ stacked,
                            float* __restrict__ meanOut) {
    int t = blockIdx.x * blockDim.x + threadIdx.x;   // [0, N_NODES*16)
    if (t >= N_NODES * 16) return;
    int n = t >> 4;
    int j = t & 15;
    float4* base = (float4*)stacked + (size_t)n * 64;
    float4 a = ((const float4*)emb)[t];
    float4 b = base[16 + j];
    float4 c = base[32 + j];
    float4 d = base[48 + j];
    base[j] = a;
    float4 s;
    s.x = 0.25f * (a.x + b.x + c.x + d.x);
    s.y = 0.25f * (a.y + b.y + c.y + d.y);
    s.z = 0.25f * (a.z + b.z + c.z + d.z);
    s.w = 0.25f * (a.w + b.w + c.w + d.w);
    ((float4*)meanOut)[t] = s;
}

// ---------- mid fallback: fp32 CSR gather ----------

__global__ void scatter_edges_int2(const int* __restrict__ rows, const int* __restrict__ cols,
                                   const float* __restrict__ vals,
                                   const int* __restrict__ row_ptr, int* __restrict__ fill,
                                   int2* __restrict__ s_colval) {
    int e = blockIdx.x * blockDim.x + threadIdx.x;
    if (e >= N_EDGES) return;
    int r = rows[e];
    int pos = row_ptr[r] + atomicAdd(&fill[r], 1);
    int2 p; p.x = cols[e]; p.y = __float_as_int(vals[e]);
    s_colval[pos] = p;
}

__global__ void __launch_bounds__(256) spmm_gather_f32(const int* __restrict__ row_ptr,
                                                       const int2* __restrict__ s_colval,
                                                       const float* __restrict__ src, int srcStride,
                                                       float* __restrict__ dst) {
    int wave = (blockIdx.x * blockDim.x + threadIdx.x) >> 6;
    if (wave >= N_NODES) return;
    int lane = threadIdx.x & 63;
    int g = lane >> 4, j = lane & 15;
    int beg = row_ptr[wave], end = row_ptr[wave + 1];
    float4 acc = make_float4(0.f, 0.f, 0.f, 0.f);
    int e = beg + g;
    for (; e + 4 < end; e += 8) {
        int2 p0 = s_colval[e], p1 = s_colval[e + 4];
        float v0 = __int_as_float(p0.y), v1 = __int_as_float(p1.y);
        float4 m0 = *(const float4*)(src + (size_t)p0.x * srcStride + j * 4);
        float4 m1 = *(const float4*)(src + (size_t)p1.x * srcStride + j * 4);
        acc.x += v0 * m0.x + v1 * m1.x; acc.y += v0 * m0.y + v1 * m1.y;
        acc.z += v0 * m0.z + v1 * m1.z; acc.w += v0 * m0.w + v1 * m1.w;
    }
    for (; e < end; e += 4) {
        int2 p = s_colval[e];
        float v = __int_as_float(p.y);
        float4 m = *(const float4*)(src + (size_t)p.x * srcStride + j * 4);
        acc.x += v * m.x; acc.y += v * m.y; acc.z += v * m.z; acc.w += v * m.w;
    }
    acc.x += __shfl_xor(acc.x, 16); acc.y += __shfl_xor(acc.y, 16);
    acc.z += __shfl_xor(acc.z, 16); acc.w += __shfl_xor(acc.w, 16);
    acc.x += __shfl_xor(acc.x, 32); acc.y += __shfl_xor(acc.y, 32);
    acc.z += __shfl_xor(acc.z, 32); acc.w += __shfl_xor(acc.w, 32);
    if (lane < 16)
        *(float4*)(dst + (size_t)wave * 256 + j * 4) = acc;
}

// ---------- last fallback: atomic scatter ----------

__global__ void init_stacked_full(const float* __restrict__ emb, float* __restrict__ stacked) {
    int t = blockIdx.x * blockDim.x + threadIdx.x;
    if (t >= N_NODES * 64) return;
    int n = t >> 6, j = t & 63;
    float4 v = (j < 16) ? ((const float4*)emb)[n * 16 + j] : make_float4(0.f, 0.f, 0.f, 0.f);
    ((float4*)stacked)[n * 64 + j] = v;
}

__global__ void spmm_atomic(const int* __restrict__ rows, const int* __restrict__ cols,
                            const float* __restrict__ vals, float* __restrict__ stacked,
                            int lprev) {
    int t = blockIdx.x * blockDim.x + threadIdx.x;
    int e = t >> 4, j = t & 15;
    if (e >= N_EDGES) return;
    int r = rows[e], c = cols[e];
    float v = vals[e];
    const float4* src = (const float4*)(stacked + (size_t)c * 256 + lprev * 64);
    float4 m = src[j];
    float* dst = stacked + (size_t)r * 256 + (lprev + 1) * 64 + j * 4;
    atomicAdd(dst + 0, v * m.x); atomicAdd(dst + 1, v * m.y);
    atomicAdd(dst + 2, v * m.z); atomicAdd(dst + 3, v * m.w);
}

__global__ void mean_layers_plain(const float* __restrict__ stacked, float* __restrict__ meanOut) {
    int t = blockIdx.x * blockDim.x + threadIdx.x;
    if (t >= N_NODES * 16) return;
    int n = t >> 4, j = t & 15;
    const float4* base = (const float4*)(stacked + (size_t)n * 256);
    float4 a = base[j], b = base[16 + j], c = base[32 + j], d = base[48 + j];
    float4 s;
    s.x = 0.25f * (a.x + b.x + c.x + d.x);
    s.y = 0.25f * (a.y + b.y + c.y + d.y);
    s.z = 0.25f * (a.z + b.z + c.z + d.z);
    s.w = 0.25f * (a.w + b.w + c.w + d.w);
    ((float4*)meanOut)[t] = s;
}

extern "C" void kernel_launch(void* const* d_in, const int* in_sizes, int n_in,
                              void* d_out, int out_size, void* d_ws, size_t ws_size,
                              hipStream_t stream) {
    const float* emb  = (const float*)d_in[0];
    const int*   rows = (const int*)d_in[1];
    const int*   cols = (const int*)d_in[2];
    const float* vals = (const float*)d_in[3];

    float* meanOut = (float*)d_out;
    float* stacked = (float*)d_out + (size_t)N_NODES * EMB_DIM;

    const size_t headInts2 = (size_t)(N_NODES * NPART + 1 + 3 * NBINS + 1);
    size_t need_bf16 = headInts2 * sizeof(int) + 64
                     + (size_t)N_EDGES * sizeof(unsigned)
                     + 2 * (size_t)N_NODES * EMB_DIM * sizeof(unsigned short);
    const size_t headInts = (size_t)(N_NODES * 2 + 1 + 2 * N_SCAN_BLOCKS);
    size_t need_f32  = headInts * sizeof(int) + 64 + (size_t)N_EDGES * sizeof(int2);

    if (ws_size >= need_bf16) {
        char* w = (char*)d_ws;
        int* rp2 = (int*)w;  w += (size_t)(N_NODES * NPART + 1) * sizeof(int);
        int* binCounts  = (int*)w;                 // NBINS
        int* bucketFill = binCounts + NBINS;       // NBINS
        int* binPtr     = binCounts + 2 * NBINS;   // NBINS+1
        w += (size_t)(3 * NBINS + 1) * sizeof(int);
        w = (char*)(((uintptr_t)w + 15) & ~(uintptr_t)15);
        unsigned* s_edges = (unsigned*)w;  w += (size_t)N_EDGES * sizeof(unsigned);
        unsigned short* mirrorA = (unsigned short*)w;  w += (size_t)N_NODES * EMB_DIM * sizeof(unsigned short);
        unsigned short* mirrorB = (unsigned short*)w;
        // Phase-A record staging aliases mirrorA+mirrorB (3.2M * 8B = 25.6 MB).
        // Mirrors are written only AFTER phaseB consumes records.
        uint2* records = (uint2*)mirrorA;

        hipMemsetAsync(binCounts, 0, (size_t)(2 * NBINS) * sizeof(int), stream);
        bin_count<<<NBCHUNKS, 256, 0, stream>>>(rows, binCounts);
        bin_scan<<<1, 512, 0, stream>>>(binCounts, binPtr);
        build_sortA<<<NCHUNKS, 256, 0, stream>>>(rows, cols, vals, binPtr, bucketFill, records);
        build_phaseB<<<NBINS, 256, 0, stream>>>(binPtr, records, s_edges, rp2);
        {
            int total = N_NODES * 16;
            int block = 256, grid = (total + block - 1) / block;
            emb_to_bf16<<<grid, block, 0, stream>>>(emb, mirrorA);
        }
        {
            long long threads = (long long)N_NODES * 64;
            int block = 256;
            int grid = (int)((threads + block - 1) / block);
            // layer 1: mirrorA -> stacked+64, mirrorB
            spmm_pass<<<grid, block, 0, stream>>>(rp2, s_edges, mirrorA, 0, 0, stacked + 64, nullptr);
            spmm_pass<<<grid, block, 0, stream>>>(rp2, s_edges, mirrorA, 1, 1, stacked + 64, nullptr);
            spmm_pass<<<grid, block, 0, stream>>>(rp2, s_edges, mirrorA, 2, 1, stacked + 64, nullptr);
            spmm_pass<<<grid, block, 0, stream>>>(rp2, s_edges, mirrorA, 3, 1, stacked + 64, mirrorB);
            // layer 2: mirrorB -> stacked+128, mirrorA
            spmm_pass<<<grid, block, 0, stream>>>(rp2, s_edges, mirrorB, 0, 0, stacked + 128, nullptr);
            spmm_pass<<<grid, block, 0, stream>>>(rp2, s_edges, mirrorB, 1, 1, stacked + 128, nullptr);
            spmm_pass<<<grid, block, 0, stream>>>(rp2, s_edges, mirrorB, 2, 1, stacked + 128, nullptr);
            spmm_pass<<<grid, block, 0, stream>>>(rp2, s_edges, mirrorB, 3, 1, stacked + 128, mirrorA);
            // layer 3: mirrorA -> stacked+192; final pass fuses l0/mean
            spmm_pass<<<grid, block, 0, stream>>>(rp2, s_edges, mirrorA, 0, 0, stacked + 192, nullptr);
            spmm_pass<<<grid, block, 0, stream>>>(rp2, s_edges, mirrorA, 1, 1, stacked + 192, nullptr);
            spmm_pass<<<grid, block, 0, stream>>>(rp2, s_edges, mirrorA, 2, 1, stacked + 192, nullptr);
            spmm_last_final<<<grid, block, 0, stream>>>(rp2, s_edges, mirrorA, emb, stacked, meanOut);
        }
    } else if (ws_size >= need_f32) {
        char* w = (char*)d_ws;
        int* counts    = (int*)w;  w += (size_t)N_NODES * sizeof(int);
        int* row_ptr   = (int*)w;  w += (size_t)(N_NODES + 1) * sizeof(int);
        int* blockSums = (int*)w;  w += (size_t)N_SCAN_BLOCKS * sizeof(int);
        int* blockOffs = (int*)w;  w += (size_t)N_SCAN_BLOCKS * sizeof(int);
        w = (char*)(((uintptr_t)w + 15) & ~(uintptr_t)15);
        int2* s_colval = (int2*)w;

        hipMemsetAsync(counts, 0, (size_t)N_NODES * sizeof(int), stream);
        {
            int block = 256, grid = (N_EDGES + block - 1) / block;
            count_rows<<<grid, block, 0, stream>>>(rows, counts);
        }
        scan_phase1<<<N_SCAN_BLOCKS, SCAN_BLOCK, 0, stream>>>(counts, blockSums);
        scan_phase2<<<1, 256, 0, stream>>>(blockSums, blockOffs, row_ptr);
        scan_phase3<<<N_SCAN_BLOCKS, SCAN_BLOCK, 0, stream>>>(counts, blockOffs, row_ptr);
        hipMemsetAsync(counts, 0, (size_t)N_NODES * sizeof(int), stream);
        {
            int block = 256, grid = (N_EDGES + block - 1) / block;
            scatter_edges_int2<<<grid, block, 0, stream>>>(rows, cols, vals, row_ptr, counts, s_colval);
        }
        {
            long long threads = (long long)N_NODES * 64;
            int block = 256;
            int grid = (int)((threads + block - 1) / block);
            spmm_gather_f32<<<grid, block, 0, stream>>>(row_ptr, s_colval, emb, 64, stacked + 1 * 64);
            spmm_gather_f32<<<grid, block, 0, stream>>>(row_ptr, s_colval, stacked + 1 * 64, 256, stacked + 2 * 64);
            spmm_gather_f32<<<grid, block, 0, stream>>>(row_ptr, s_colval, stacked + 2 * 64, 256, stacked + 3 * 64);
        }
        {
            int total = N_NODES * 16;
            int block = 256, grid = (total + block - 1) / block;
            mean_layers<<<grid, block, 0, stream>>>(emb, stacked, meanOut);
        }
    } else {
        {
            int total = N_NODES * 64;
            int block = 256, grid = (total + block - 1) / block;
            init_stacked_full<<<grid, block, 0, stream>>>(emb, stacked);
        }
        {
            long long total = (long long)N_EDGES * 16;
            int block = 256, grid = (int)((total + block - 1) / block);
            for (int l = 0; l < N_LAYERS; ++l)
                spmm_atomic<<<grid, block, 0, stream>>>(rows, cols, vals, stacked, l);
        }
        {
            int total = N_NODES * 16;
            int block = 256, grid = (total + block - 1) / block;
            mean_layers_plain<<<grid, block, 0, stream>>>(stacked, meanOut);
        }
    }
}

// Round 10
// 589.295 us; speedup vs baseline: 1.3907x; 1.3907x over previous
//
#include <hip/hip_runtime.h>
#include <hip/hip_fp16.h>

#define N_NODES 100000
#define EMB_DIM 64
#define N_EDGES 3200000
#define N_LAYERS 3

#define SCAN_BLOCK 512
#define N_SCAN_BLOCKS ((N_NODES + SCAN_BLOCK - 1) / SCAN_BLOCK)   // 196

// Coarse bins for the two-phase CSR build.
#define ABINROWS 256
#define NBINS ((N_NODES + ABINROWS - 1) / ABINROWS)   // 391
#define ACH2 4096
#define NCHUNKS2 ((N_EDGES + ACH2 - 1) / ACH2)        // 782
#define BCHUNK 4096
#define NBCHUNKS ((N_EDGES + BCHUNK - 1) / BCHUNK)    // 782

// d_out layout: mean [N_NODES*64] first, then stacked [N_NODES*4*64]
// stacked[n][l][d] at n*256 + l*64 + d

typedef float f32x4 __attribute__((ext_vector_type(4)));
typedef unsigned short u16x4 __attribute__((ext_vector_type(4)));

__device__ __forceinline__ unsigned short f32_to_bf16_rtn(float f) {
    unsigned u = __float_as_uint(f);
    unsigned r = u + 0x7FFFu + ((u >> 16) & 1u);
    return (unsigned short)(r >> 16);
}
__device__ __forceinline__ float bf16_to_f32(unsigned short h) {
    return __uint_as_float(((unsigned)h) << 16);
}

// ---------- bin-level counting ----------

__global__ void __launch_bounds__(256) bin_count(const int* __restrict__ rows,
                                                 int* __restrict__ binCounts) {
    __shared__ int h[NBINS];
    int t = threadIdx.x;
    for (int i = t; i < NBINS; i += 256) h[i] = 0;
    __syncthreads();
    int base = blockIdx.x * BCHUNK;
    int n = N_EDGES - base; if (n > BCHUNK) n = BCHUNK;
    for (int i = t; i < n; i += 256)
        atomicAdd(&h[__builtin_nontemporal_load(rows + base + i) >> 8], 1);
    __syncthreads();
    for (int i = t; i < NBINS; i += 256) {
        int c = h[i];
        if (c) atomicAdd(&binCounts[i], c);
    }
}

__global__ void __launch_bounds__(512) bin_scan(const int* __restrict__ binCounts,
                                                int* __restrict__ binPtr) {
    __shared__ int sm[512];
    int t = threadIdx.x;
    int v = (t < NBINS) ? binCounts[t] : 0;
    sm[t] = v;
    __syncthreads();
    for (int off = 1; off < 512; off <<= 1) {
        int u = (t >= off) ? sm[t - off] : 0;
        __syncthreads();
        sm[t] += u;
        __syncthreads();
    }
    if (t < NBINS) binPtr[t + 1] = sm[t];
    if (t == 0) binPtr[0] = 0;
}

// ---------- legacy per-row count + scan (f32 fallback path only) ----------

__global__ void count_rows(const int* __restrict__ rows, int* __restrict__ counts) {
    int e = blockIdx.x * blockDim.x + threadIdx.x;
    if (e >= N_EDGES) return;
    atomicAdd(&counts[rows[e]], 1);
}

__global__ void __launch_bounds__(SCAN_BLOCK) scan_phase1(const int* __restrict__ counts,
                                                          int* __restrict__ blockSums) {
    __shared__ int sm[SCAN_BLOCK];
    int idx = blockIdx.x * SCAN_BLOCK + threadIdx.x;
    int v = (idx < N_NODES) ? counts[idx] : 0;
    sm[threadIdx.x] = v;
    __syncthreads();
    for (int off = SCAN_BLOCK / 2; off > 0; off >>= 1) {
        if (threadIdx.x < off) sm[threadIdx.x] += sm[threadIdx.x + off];
        __syncthreads();
    }
    if (threadIdx.x == 0) blockSums[blockIdx.x] = sm[0];
}

__global__ void __launch_bounds__(256) scan_phase2(const int* __restrict__ blockSums,
                                                   int* __restrict__ blockOffs,
                                                   int* __restrict__ row_ptr) {
    __shared__ int sm[256];
    int t = threadIdx.x;
    int v = (t < N_SCAN_BLOCKS) ? blockSums[t] : 0;
    sm[t] = v;
    __syncthreads();
    for (int off = 1; off < 256; off <<= 1) {
        int u = (t >= off) ? sm[t - off] : 0;
        __syncthreads();
        sm[t] += u;
        __syncthreads();
    }
    if (t < N_SCAN_BLOCKS) blockOffs[t] = (t == 0) ? 0 : sm[t - 1];
    if (t == 255) row_ptr[N_NODES] = sm[255];
}

__global__ void __launch_bounds__(SCAN_BLOCK) scan_phase3(const int* __restrict__ counts,
                                                          const int* __restrict__ blockOffs,
                                                          int* __restrict__ row_ptr) {
    __shared__ int sm[SCAN_BLOCK];
    int idx = blockIdx.x * SCAN_BLOCK + threadIdx.x;
    int t = threadIdx.x;
    int v = (idx < N_NODES) ? counts[idx] : 0;
    sm[t] = v;
    __syncthreads();
    for (int off = 1; off < SCAN_BLOCK; off <<= 1) {
        int u = (t >= off) ? sm[t - off] : 0;
        __syncthreads();
        sm[t] += u;
        __syncthreads();
    }
    if (idx < N_NODES) row_ptr[idx] = blockOffs[blockIdx.x] + sm[t] - v;
}

// ---------- phase A: scan-free two-pass bin partition (dense run writes) ----------
// Pass 1: LDS histogram of this chunk (4.7 KB LDS, no staging buf, no scan).
// Reserve one contiguous global run per non-empty bin (1 atomic each).
// Pass 2: re-read the chunk (L2-hot, ~48 KB) and write each record at
// runBase + LDS cursor -> run-dense lines (~10.5 records/run), WG-owned.
// Replaces the R5-R8 LDS counting-sort: 86 us, 18 barriers, 24.6 KB LDS,
// 1.38M bank conflicts -> 3 barriers, max occupancy. Pattern correctness
// proven in R7 (same structure, different bin width).
// Packed edge: col (17 bits) << 15 | fp16(val) low 15 bits (val>=0 so sign=0).

__global__ void __launch_bounds__(256) build_sort2(const int* __restrict__ rows,
                                                   const int* __restrict__ cols,
                                                   const float* __restrict__ vals,
                                                   const int* __restrict__ binPtr,
                                                   int* __restrict__ bucketFill,
                                                   uint2* __restrict__ records) {
    __shared__ int binCnt[NBINS];
    __shared__ int binCur[NBINS];
    __shared__ int binG[NBINS];
    int base = blockIdx.x * ACH2;
    int n = N_EDGES - base; if (n > ACH2) n = ACH2;
    int t = threadIdx.x;

    for (int i = t; i < NBINS; i += 256) { binCnt[i] = 0; binCur[i] = 0; }
    __syncthreads();
    for (int i = t; i < n; i += 256) atomicAdd(&binCnt[rows[base + i] >> 8], 1);
    __syncthreads();
    for (int b = t; b < NBINS; b += 256) {
        int c = binCnt[b];
        if (c) binG[b] = binPtr[b] + atomicAdd(&bucketFill[b], c);
    }
    __syncthreads();
    for (int i = t; i < n; i += 256) {
        int e = base + i;
        int r = rows[e];                              // L2-hot re-read
        int b = r >> 8;
        unsigned hb = __half_as_ushort(__float2half(vals[e]));
        unsigned pk = (((unsigned)cols[e]) << 15) | (hb & 0x7FFFu);
        int pos = binG[b] + atomicAdd(&binCur[b], 1);
        records[pos] = make_uint2((unsigned)r, pk);
    }
}

// ---------- phase B: per-bin row_ptr derivation + scatter to exact CSR slots ----------
__global__ void __launch_bounds__(256) build_phaseB(const int* __restrict__ binPtr,
                                                    const uint2* __restrict__ records,
                                                    unsigned* __restrict__ s_edges,
                                                    int* __restrict__ row_ptr) {
    __shared__ int lcnt[ABINROWS];
    __shared__ int linc[ABINROWS];
    __shared__ int lrp[ABINROWS];
    __shared__ int lfill[ABINROWS];
    int b = blockIdx.x;
    int t = threadIdx.x;
    int r0 = b * ABINROWS;
    int r1 = r0 + ABINROWS; if (r1 > N_NODES) r1 = N_NODES;
    int nr = r1 - r0;
    int beg = binPtr[b];
    int end = binPtr[b + 1];

    lcnt[t] = 0; lfill[t] = 0;
    __syncthreads();
    // Pass 1: per-row histogram.
    for (int i = beg + t; i < end; i += 256) {
        atomicAdd(&lcnt[(int)records[i].x - r0], 1);
    }
    __syncthreads();
    // Inclusive scan of 256 entries.
    linc[t] = lcnt[t];
    __syncthreads();
    for (int off = 1; off < 256; off <<= 1) {
        int u = (t >= off) ? linc[t - off] : 0;
        __syncthreads();
        linc[t] += u;
        __syncthreads();
    }
    lrp[t] = beg + linc[t] - lcnt[t];   // exclusive prefix + bin base
    if (t < nr) row_ptr[r0 + t] = lrp[t];
    if (t == 0) row_ptr[r0 + nr] = end;
    __syncthreads();
    // Pass 2: scatter (records re-read is L2-resident).
    for (int i = beg + t; i < end; i += 256) {
        uint2 rec = records[i];
        int lr = (int)rec.x - r0;
        int lp = atomicAdd(&lfill[lr], 1);
        s_edges[lrp[lr] + lp] = rec.y;
    }
}

// ---------- emb -> bf16 mirror (pure stream: nt both sides) ----------
__global__ void emb_to_bf16(const float* __restrict__ emb, unsigned short* __restrict__ mirror) {
    int t = blockIdx.x * blockDim.x + threadIdx.x;   // [0, N_NODES*16)
    if (t >= N_NODES * 16) return;
    f32x4 v = __builtin_nontemporal_load((const f32x4*)emb + t);
    u16x4 o;
    o.x = f32_to_bf16_rtn(v.x); o.y = f32_to_bf16_rtn(v.y);
    o.z = f32_to_bf16_rtn(v.z); o.w = f32_to_bf16_rtn(v.w);
    __builtin_nontemporal_store(o, (u16x4*)mirror + t);
}

// ---------- SpMM gather core, bf16 source: one wave per destination node ----------
// 4 groups x 16 lanes; lane j of a group owns bf16x4 chunk j of the 64-dim row.
// Edge words staged via ONE coalesced per-lane load (nt: no reuse), distributed
// with __shfl. Mirror gathers use normal cached loads (the only data with reuse).
// Control flow is wave-uniform (shfl from inactive lanes is undefined on CDNA).

__device__ __forceinline__ void gacc(float4& acc, unsigned p, int j,
                                     const unsigned short* __restrict__ srcMirror) {
    float v = __half2float(__ushort_as_half((unsigned short)(p & 0x7FFFu)));
    ushort4 m = *(const ushort4*)(srcMirror + (size_t)(p >> 15) * 64 + j * 4);
    acc.x += v * bf16_to_f32(m.x);
    acc.y += v * bf16_to_f32(m.y);
    acc.z += v * bf16_to_f32(m.z);
    acc.w += v * bf16_to_f32(m.w);
}

__device__ __forceinline__ float4 spmm_row_core(int beg, int end, int g, int j, int lane,
                                                const unsigned* __restrict__ s_edges,
                                                const unsigned short* __restrict__ srcMirror) {
    int deg = end - beg;                  // wave-uniform
    unsigned ew = (lane < deg) ? __builtin_nontemporal_load(s_edges + beg + lane) : 0u;
    float4 acc = make_float4(0.f, 0.f, 0.f, 0.f);
    int nfull = deg < 64 ? deg : 64;      // wave-uniform
    for (int kb = 0; kb < nfull; kb += 16) {
        int k0 = kb + g, k1 = kb + g + 4, k2 = kb + g + 8, k3 = kb + g + 12;
        unsigned p0 = __shfl(ew, k0);
        unsigned p1 = __shfl(ew, k1);
        unsigned p2 = __shfl(ew, k2);
        unsigned p3 = __shfl(ew, k3);
        if (k0 < nfull) gacc(acc, p0, j, srcMirror);
        if (k1 < nfull) gacc(acc, p1, j, srcMirror);
        if (k2 < nfull) gacc(acc, p2, j, srcMirror);
        if (k3 < nfull) gacc(acc, p3, j, srcMirror);
    }
    for (int e = beg + 64 + g; e < end; e += 4) {
        unsigned p = s_edges[e];
        gacc(acc, p, j, srcMirror);
    }
    acc.x += __shfl_xor(acc.x, 16); acc.y += __shfl_xor(acc.y, 16);
    acc.z += __shfl_xor(acc.z, 16); acc.w += __shfl_xor(acc.w, 16);
    acc.x += __shfl_xor(acc.x, 32); acc.y += __shfl_xor(acc.y, 32);
    acc.z += __shfl_xor(acc.z, 32); acc.w += __shfl_xor(acc.w, 32);
    return acc;
}

__global__ void __launch_bounds__(256) spmm_gather_bf16_mid(const int* __restrict__ row_ptr,
                                                            const unsigned* __restrict__ s_edges,
                                                            const unsigned short* __restrict__ srcMirror,
                                                            float* __restrict__ dstStacked,
                                                            unsigned short* __restrict__ dstMirror) {
    int wave = (blockIdx.x * blockDim.x + threadIdx.x) >> 6;
    if (wave >= N_NODES) return;
    int lane = threadIdx.x & 63;
    int g = lane >> 4, j = lane & 15;
    float4 acc = spmm_row_core(row_ptr[wave], row_ptr[wave + 1], g, j, lane, s_edges, srcMirror);
    if (lane < 16) {
        f32x4 vv = {acc.x, acc.y, acc.z, acc.w};
        __builtin_nontemporal_store(vv, (f32x4*)(dstStacked + (size_t)wave * 256 + j * 4));
        u16x4 o;
        o.x = f32_to_bf16_rtn(acc.x); o.y = f32_to_bf16_rtn(acc.y);
        o.z = f32_to_bf16_rtn(acc.z); o.w = f32_to_bf16_rtn(acc.w);
        __builtin_nontemporal_store(o, (u16x4*)(dstMirror + (size_t)wave * 64 + j * 4));
    }
}

// Last layer: fuse the 4-layer mean + layer-0 copy into the same dispatch.
__global__ void __launch_bounds__(256) spmm_gather_bf16_last(const int* __restrict__ row_ptr,
                                                             const unsigned* __restrict__ s_edges,
                                                             const unsigned short* __restrict__ srcMirror,
                                                             const float* __restrict__ emb,
                                                             float* __restrict__ stacked,
                                                             float* __restrict__ meanOut) {
    int wave = (blockIdx.x * blockDim.x + threadIdx.x) >> 6;
    if (wave >= N_NODES) return;
    int lane = threadIdx.x & 63;
    int g = lane >> 4, j = lane & 15;
    float4 acc = spmm_row_core(row_ptr[wave], row_ptr[wave + 1], g, j, lane, s_edges, srcMirror);
    if (lane < 16) {
        float* base = stacked + (size_t)wave * 256 + j * 4;
        f32x4 a  = __builtin_nontemporal_load((const f32x4*)(emb + (size_t)wave * 64 + j * 4));
        f32x4 b1 = __builtin_nontemporal_load((const f32x4*)(base + 64));
        f32x4 c2 = __builtin_nontemporal_load((const f32x4*)(base + 128));
        f32x4 d3 = {acc.x, acc.y, acc.z, acc.w};
        __builtin_nontemporal_store(a, (f32x4*)base);            // layer 0
        __builtin_nontemporal_store(d3, (f32x4*)(base + 192));   // layer 3
        f32x4 s;
        s.x = 0.25f * (a.x + b1.x + c2.x + d3.x);
        s.y = 0.25f * (a.y + b1.y + c2.y + d3.y);
        s.z = 0.25f * (a.z + b1.z + c2.z + d3.z);
        s.w = 0.25f * (a.w + b1.w + c2.w + d3.w);
        __builtin_nontemporal_store(s, (f32x4*)(meanOut + (size_t)wave * 64 + j * 4));
    }
}

// ---------- mean over 4 layers (f32 fallback path) ----------
__global__ void mean_layers(const float* __restrict__ emb,
                            float* __restrict__ stacked,
                            float* __restrict__ meanOut) {
    int t = blockIdx.x * blockDim.x + threadIdx.x;   // [0, N_NODES*16)
    if (t >= N_NODES * 16) return;
    int n = t >> 4;
    int j = t & 15;
    float4* base = (float4*)stacked + (size_t)n * 64;
    float4 a = ((const float4*)emb)[t];
    float4 b = base[16 + j];
    float4 c = base[32 + j];
    float4 d = base[48 + j];
    base[j] = a;
    float4 s;
    s.x = 0.25f * (a.x + b.x + c.x + d.x);
    s.y = 0.25f * (a.y + b.y + c.y + d.y);
    s.z = 0.25f * (a.z + b.z + c.z + d.z);
    s.w = 0.25f * (a.w + b.w + c.w + d.w);
    ((float4*)meanOut)[t] = s;
}

// ---------- mid fallback: fp32 CSR gather ----------

__global__ void scatter_edges_int2(const int* __restrict__ rows, const int* __restrict__ cols,
                                   const float* __restrict__ vals,
                                   const int* __restrict__ row_ptr, int* __restrict__ fill,
                                   int2* __restrict__ s_colval) {
    int e = blockIdx.x * blockDim.x + threadIdx.x;
    if (e >= N_EDGES) return;
    int r = rows[e];
    int pos = row_ptr[r] + atomicAdd(&fill[r], 1);
    int2 p; p.x = cols[e]; p.y = __float_as_int(vals[e]);
    s_colval[pos] = p;
}

__global__ void __launch_bounds__(256) spmm_gather_f32(const int* __restrict__ row_ptr,
                                                       const int2* __restrict__ s_colval,
                                                       const float* __restrict__ src, int srcStride,
                                                       float* __restrict__ dst) {
    int wave = (blockIdx.x * blockDim.x + threadIdx.x) >> 6;
    if (wave >= N_NODES) return;
    int lane = threadIdx.x & 63;
    int g = lane >> 4, j = lane & 15;
    int beg = row_ptr[wave], end = row_ptr[wave + 1];
    float4 acc = make_float4(0.f, 0.f, 0.f, 0.f);
    int e = beg + g;
    for (; e + 4 < end; e += 8) {
        int2 p0 = s_colval[e], p1 = s_colval[e + 4];
        float v0 = __int_as_float(p0.y), v1 = __int_as_float(p1.y);
        float4 m0 = *(const float4*)(src + (size_t)p0.x * srcStride + j * 4);
        float4 m1 = *(const float4*)(src + (size_t)p1.x * srcStride + j * 4);
        acc.x += v0 * m0.x + v1 * m1.x; acc.y += v0 * m0.y + v1 * m1.y;
        acc.z += v0 * m0.z + v1 * m1.z; acc.w += v0 * m0.w + v1 * m1.w;
    }
    for (; e < end; e += 4) {
        int2 p = s_colval[e];
        float v = __int_as_float(p.y);
        float4 m = *(const float4*)(src + (size_t)p.x * srcStride + j * 4);
        acc.x += v * m.x; acc.y += v * m.y; acc.z += v * m.z; acc.w += v * m.w;
    }
    acc.x += __shfl_xor(acc.x, 16); acc.y += __shfl_xor(acc.y, 16);
    acc.z += __shfl_xor(acc.z, 16); acc.w += __shfl_xor(acc.w, 16);
    acc.x += __shfl_xor(acc.x, 32); acc.y += __shfl_xor(acc.y, 32);
    acc.z += __shfl_xor(acc.z, 32); acc.w += __shfl_xor(acc.w, 32);
    if (lane < 16)
        *(float4*)(dst + (size_t)wave * 256 + j * 4) = acc;
}

// ---------- last fallback: atomic scatter ----------

__global__ void init_stacked_full(const float* __restrict__ emb, float* __restrict__ stacked) {
    int t = blockIdx.x * blockDim.x + threadIdx.x;
    if (t >= N_NODES * 64) return;
    int n = t >> 6, j = t & 63;
    float4 v = (j < 16) ? ((const float4*)emb)[n * 16 + j] : make_float4(0.f, 0.f, 0.f, 0.f);
    ((float4*)stacked)[n * 64 + j] = v;
}

__global__ void spmm_atomic(const int* __restrict__ rows, const int* __restrict__ cols,
                            const float* __restrict__ vals, float* __restrict__ stacked,
                            int lprev) {
    int t = blockIdx.x * blockDim.x + threadIdx.x;
    int e = t >> 4, j = t & 15;
    if (e >= N_EDGES) return;
    int r = rows[e], c = cols[e];
    float v = vals[e];
    const float4* src = (const float4*)(stacked + (size_t)c * 256 + lprev * 64);
    float4 m = src[j];
    float* dst = stacked + (size_t)r * 256 + (lprev + 1) * 64 + j * 4;
    atomicAdd(dst + 0, v * m.x); atomicAdd(dst + 1, v * m.y);
    atomicAdd(dst + 2, v * m.z); atomicAdd(dst + 3, v * m.w);
}

__global__ void mean_layers_plain(const float* __restrict__ stacked, float* __restrict__ meanOut) {
    int t = blockIdx.x * blockDim.x + threadIdx.x;
    if (t >= N_NODES * 16) return;
    int n = t >> 4, j = t & 15;
    const float4* base = (const float4*)(stacked + (size_t)n * 256);
    float4 a = base[j], b = base[16 + j], c = base[32 + j], d = base[48 + j];
    float4 s;
    s.x = 0.25f * (a.x + b.x + c.x + d.x);
    s.y = 0.25f * (a.y + b.y + c.y + d.y);
    s.z = 0.25f * (a.z + b.z + c.z + d.z);
    s.w = 0.25f * (a.w + b.w + c.w + d.w);
    ((float4*)meanOut)[t] = s;
}

extern "C" void kernel_launch(void* const* d_in, const int* in_sizes, int n_in,
                              void* d_out, int out_size, void* d_ws, size_t ws_size,
                              hipStream_t stream) {
    const float* emb  = (const float*)d_in[0];
    const int*   rows = (const int*)d_in[1];
    const int*   cols = (const int*)d_in[2];
    const float* vals = (const float*)d_in[3];

    float* meanOut = (float*)d_out;
    float* stacked = (float*)d_out + (size_t)N_NODES * EMB_DIM;

    const size_t headInts = (size_t)(N_NODES * 2 + 1 + 2 * N_SCAN_BLOCKS);
    size_t need_bf16 = headInts * sizeof(int) + 64
                     + (size_t)N_EDGES * sizeof(unsigned)
                     + 2 * (size_t)N_NODES * EMB_DIM * sizeof(unsigned short);
    size_t need_f32  = headInts * sizeof(int) + 64 + (size_t)N_EDGES * sizeof(int2);

    if (ws_size >= need_bf16) {
        char* w = (char*)d_ws;
        int* counts    = (int*)w;  w += (size_t)N_NODES * sizeof(int);
        int* row_ptr   = (int*)w;  w += (size_t)(N_NODES + 1) * sizeof(int);
        int* blockSums = (int*)w;  w += (size_t)N_SCAN_BLOCKS * sizeof(int);
        int* blockOffs = (int*)w;  w += (size_t)N_SCAN_BLOCKS * sizeof(int);
        w = (char*)(((uintptr_t)w + 15) & ~(uintptr_t)15);
        unsigned* s_edges = (unsigned*)w;  w += (size_t)N_EDGES * sizeof(unsigned);
        unsigned short* mirrorA = (unsigned short*)w;  w += (size_t)N_NODES * EMB_DIM * sizeof(unsigned short);
        unsigned short* mirrorB = (unsigned short*)w;
        // Phase-A record staging aliases mirrorA+mirrorB (3.2M * 8B = 25.6 MB).
        // Mirrors are written only AFTER phaseB consumes records.
        uint2* records = (uint2*)mirrorA;
        // Bin-level arrays live in the (otherwise unused) counts region.
        int* binCounts  = counts;                 // NBINS
        int* bucketFill = counts + NBINS;         // NBINS
        int* binPtr     = counts + 2 * NBINS;     // NBINS+1

        hipMemsetAsync(counts, 0, (size_t)(2 * NBINS) * sizeof(int), stream);
        bin_count<<<NBCHUNKS, 256, 0, stream>>>(rows, binCounts);
        bin_scan<<<1, 512, 0, stream>>>(binCounts, binPtr);
        build_sort2<<<NCHUNKS2, 256, 0, stream>>>(rows, cols, vals, binPtr, bucketFill, records);
        build_phaseB<<<NBINS, 256, 0, stream>>>(binPtr, records, s_edges, row_ptr);
        {
            int total = N_NODES * 16;
            int block = 256, grid = (total + block - 1) / block;
            emb_to_bf16<<<grid, block, 0, stream>>>(emb, mirrorA);
        }
        {
            long long threads = (long long)N_NODES * 64;
            int block = 256;
            int grid = (int)((threads + block - 1) / block);
            spmm_gather_bf16_mid<<<grid, block, 0, stream>>>(row_ptr, s_edges, mirrorA, stacked + 1 * 64, mirrorB);
            spmm_gather_bf16_mid<<<grid, block, 0, stream>>>(row_ptr, s_edges, mirrorB, stacked + 2 * 64, mirrorA);
            spmm_gather_bf16_last<<<grid, block, 0, stream>>>(row_ptr, s_edges, mirrorA, emb, stacked, meanOut);
        }
    } else if (ws_size >= need_f32) {
        char* w = (char*)d_ws;
        int* counts    = (int*)w;  w += (size_t)N_NODES * sizeof(int);
        int* row_ptr   = (int*)w;  w += (size_t)(N_NODES + 1) * sizeof(int);
        int* blockSums = (int*)w;  w += (size_t)N_SCAN_BLOCKS * sizeof(int);
        int* blockOffs = (int*)w;  w += (size_t)N_SCAN_BLOCKS * sizeof(int);
        w = (char*)(((uintptr_t)w + 15) & ~(uintptr_t)15);
        int2* s_colval = (int2*)w;

        hipMemsetAsync(counts, 0, (size_t)N_NODES * sizeof(int), stream);
        {
            int block = 256, grid = (N_EDGES + block - 1) / block;
            count_rows<<<grid, block, 0, stream>>>(rows, counts);
        }
        scan_phase1<<<N_SCAN_BLOCKS, SCAN_BLOCK, 0, stream>>>(counts, blockSums);
        scan_phase2<<<1, 256, 0, stream>>>(blockSums, blockOffs, row_ptr);
        scan_phase3<<<N_SCAN_BLOCKS, SCAN_BLOCK, 0, stream>>>(counts, blockOffs, row_ptr);
        hipMemsetAsync(counts, 0, (size_t)N_NODES * sizeof(int), stream);
        {
            int block = 256, grid = (N_EDGES + block - 1) / block;
            scatter_edges_int2<<<grid, block, 0, stream>>>(rows, cols, vals, row_ptr, counts, s_colval);
        }
        {
            long long threads = (long long)N_NODES * 64;
            int block = 256;
            int grid = (int)((threads + block - 1) / block);
            spmm_gather_f32<<<grid, block, 0, stream>>>(row_ptr, s_colval, emb, 64, stacked + 1 * 64);
            spmm_gather_f32<<<grid, block, 0, stream>>>(row_ptr, s_colval, stacked + 1 * 64, 256, stacked + 2 * 64);
            spmm_gather_f32<<<grid, block, 0, stream>>>(row_ptr, s_colval, stacked + 2 * 64, 256, stacked + 3 * 64);
        }
        {
            int total = N_NODES * 16;
            int block = 256, grid = (total + block - 1) / block;
            mean_layers<<<grid, block, 0, stream>>>(emb, stacked, meanOut);
        }
    } else {
        {
            int total = N_NODES * 64;
            int block = 256, grid = (total + block - 1) / block;
            init_stacked_full<<<grid, block, 0, stream>>>(emb, stacked);
        }
        {
            long long total = (long long)N_EDGES * 16;
            int block = 256, grid = (int)((total + block - 1) / block);
            for (int l = 0; l < N_LAYERS; ++l)
                spmm_atomic<<<grid, block, 0, stream>>>(rows, cols, vals, stacked, l);
        }
        {
            int total = N_NODES * 16;
            int block = 256, grid = (total + block - 1) / block;
            mean_layers_plain<<<grid, block, 0, stream>>>(stacked, meanOut);
        }
    }
}

// Round 11
// 566.938 us; speedup vs baseline: 1.4455x; 1.0394x over previous
//
#include <hip/hip_runtime.h>
#include <hip/hip_fp16.h>

#define N_NODES 100000
#define EMB_DIM 64
#define N_EDGES 3200000
#define N_LAYERS 3

#define SCAN_BLOCK 512
#define N_SCAN_BLOCKS ((N_NODES + SCAN_BLOCK - 1) / SCAN_BLOCK)   // 196

// Coarse bins for the two-phase CSR build.
#define ABINROWS 256
#define NBINS ((N_NODES + ABINROWS - 1) / ABINROWS)   // 391
#define NBINS_P 512
#define ACHUNK 2048
#define AEPT 8
#define NCHUNKS ((N_EDGES + ACHUNK - 1) / ACHUNK)     // 1563
#define BCHUNK 4096
#define NBCHUNKS ((N_EDGES + BCHUNK - 1) / BCHUNK)    // 782

// d_out layout: mean [N_NODES*64] first, then stacked [N_NODES*4*64]
// stacked[n][l][d] at n*256 + l*64 + d

typedef float f32x4 __attribute__((ext_vector_type(4)));
typedef unsigned short u16x4 __attribute__((ext_vector_type(4)));

__device__ __forceinline__ unsigned short f32_to_bf16_rtn(float f) {
    unsigned u = __float_as_uint(f);
    unsigned r = u + 0x7FFFu + ((u >> 16) & 1u);
    return (unsigned short)(r >> 16);
}
__device__ __forceinline__ float bf16_to_f32(unsigned short h) {
    return __uint_as_float(((unsigned)h) << 16);
}

// Wave-level inclusive scan (64 lanes). All lanes of the wave must be active.
__device__ __forceinline__ int wave_incl_scan(int v, int lane) {
#pragma unroll
    for (int d = 1; d < 64; d <<= 1) {
        int u = __shfl_up(v, d);
        if (lane >= d) v += u;
    }
    return v;
}

// ---------- bin-level counting ----------

__global__ void __launch_bounds__(256) bin_count(const int* __restrict__ rows,
                                                 int* __restrict__ binCounts) {
    __shared__ int h[NBINS];
    int t = threadIdx.x;
    for (int i = t; i < NBINS; i += 256) h[i] = 0;
    __syncthreads();
    int base = blockIdx.x * BCHUNK;
    int n = N_EDGES - base; if (n > BCHUNK) n = BCHUNK;
    for (int i = t; i < n; i += 256)
        atomicAdd(&h[__builtin_nontemporal_load(rows + base + i) >> 8], 1);
    __syncthreads();
    for (int i = t; i < NBINS; i += 256) {
        int c = h[i];
        if (c) atomicAdd(&binCounts[i], c);
    }
}

__global__ void __launch_bounds__(512) bin_scan(const int* __restrict__ binCounts,
                                                int* __restrict__ binPtr) {
    __shared__ int sm[512];
    int t = threadIdx.x;
    int v = (t < NBINS) ? binCounts[t] : 0;
    sm[t] = v;
    __syncthreads();
    for (int off = 1; off < 512; off <<= 1) {
        int u = (t >= off) ? sm[t - off] : 0;
        __syncthreads();
        sm[t] += u;
        __syncthreads();
    }
    if (t < NBINS) binPtr[t + 1] = sm[t];
    if (t == 0) binPtr[0] = 0;
}

// ---------- legacy per-row count + scan (f32 fallback path only) ----------

__global__ void count_rows(const int* __restrict__ rows, int* __restrict__ counts) {
    int e = blockIdx.x * blockDim.x + threadIdx.x;
    if (e >= N_EDGES) return;
    atomicAdd(&counts[rows[e]], 1);
}

__global__ void __launch_bounds__(SCAN_BLOCK) scan_phase1(const int* __restrict__ counts,
                                                          int* __restrict__ blockSums) {
    __shared__ int sm[SCAN_BLOCK];
    int idx = blockIdx.x * SCAN_BLOCK + threadIdx.x;
    int v = (idx < N_NODES) ? counts[idx] : 0;
    sm[threadIdx.x] = v;
    __syncthreads();
    for (int off = SCAN_BLOCK / 2; off > 0; off >>= 1) {
        if (threadIdx.x < off) sm[threadIdx.x] += sm[threadIdx.x + off];
        __syncthreads();
    }
    if (threadIdx.x == 0) blockSums[blockIdx.x] = sm[0];
}

__global__ void __launch_bounds__(256) scan_phase2(const int* __restrict__ blockSums,
                                                   int* __restrict__ blockOffs,
                                                   int* __restrict__ row_ptr) {
    __shared__ int sm[256];
    int t = threadIdx.x;
    int v = (t < N_SCAN_BLOCKS) ? blockSums[t] : 0;
    sm[t] = v;
    __syncthreads();
    for (int off = 1; off < 256; off <<= 1) {
        int u = (t >= off) ? sm[t - off] : 0;
        __syncthreads();
        sm[t] += u;
        __syncthreads();
    }
    if (t < N_SCAN_BLOCKS) blockOffs[t] = (t == 0) ? 0 : sm[t - 1];
    if (t == 255) row_ptr[N_NODES] = sm[255];
}

__global__ void __launch_bounds__(SCAN_BLOCK) scan_phase3(const int* __restrict__ counts,
                                                          const int* __restrict__ blockOffs,
                                                          int* __restrict__ row_ptr) {
    __shared__ int sm[SCAN_BLOCK];
    int idx = blockIdx.x * SCAN_BLOCK + threadIdx.x;
    int t = threadIdx.x;
    int v = (idx < N_NODES) ? counts[idx] : 0;
    sm[t] = v;
    __syncthreads();
    for (int off = 1; off < SCAN_BLOCK; off <<= 1) {
        int u = (t >= off) ? sm[t - off] : 0;
        __syncthreads();
        sm[t] += u;
        __syncthreads();
    }
    if (idx < N_NODES) row_ptr[idx] = blockOffs[blockIdx.x] + sm[t] - v;
}

// ---------- phase A: LDS counting-sort partition (dense run writes) ----------
// R11: wave-shfl scan replaces the 18-barrier Hillis-Steele (R9 counters:
// occupancy 42%, VALUBusy 6.5% -> barrier-wait bound). Structure otherwise
// identical to R8's sortA (LDS staging -> sequential full-line copy-out,
// WRITE ~38 MB; do NOT regress to direct scatter, R10 showed 91 MB).
// Packed edge: col (17 bits) << 15 | fp16(val) low 15 bits (val>=0 so sign=0).

__global__ void __launch_bounds__(256) build_sortA(const int* __restrict__ rows,
                                                   const int* __restrict__ cols,
                                                   const float* __restrict__ vals,
                                                   const int* __restrict__ binPtr,
                                                   int* __restrict__ bucketFill,
                                                   uint2* __restrict__ records) {
    __shared__ int binCnt[NBINS_P];
    __shared__ int binExc[NBINS_P];   // exclusive prefix of binCnt
    __shared__ int binCur[NBINS_P];
    __shared__ int binG[NBINS];       // global dst base of this WG's run per bin
    __shared__ int wtot[4];
    __shared__ uint2 buf[ACHUNK];     // bin-sorted records

    int base = blockIdx.x * ACHUNK;
    int n = N_EDGES - base; if (n > ACHUNK) n = ACHUNK;
    int t = threadIdx.x;
    int lane = t & 63, w = t >> 6;

    for (int i = t; i < NBINS_P; i += 256) { binCnt[i] = 0; binCur[i] = 0; }
    __syncthreads();

    // Load AEPT edges/thread (static unroll -> registers) + histogram.
    int r_[AEPT]; unsigned pk_[AEPT];
#pragma unroll AEPT
    for (int k = 0; k < AEPT; ++k) {
        int i = t + k * 256;
        r_[k] = 0; pk_[k] = 0;
        if (i < n) {
            int e = base + i;
            int r = __builtin_nontemporal_load(rows + e);
            unsigned hb = __half_as_ushort(__float2half(__builtin_nontemporal_load(vals + e)));
            r_[k] = r;
            pk_[k] = (((unsigned)__builtin_nontemporal_load(cols + e)) << 15) | (hb & 0x7FFFu);
            atomicAdd(&binCnt[r >> 8], 1);
        }
    }
    __syncthreads();

    // Wave-level scan over 512 entries: thread t owns entries 2t, 2t+1
    // (wave w covers contiguous entries [128w, 128w+128)).
    int c0 = binCnt[2 * t], c1 = binCnt[2 * t + 1];
    int s = c0 + c1;
    int incl = wave_incl_scan(s, lane);
    if (lane == 63) wtot[w] = incl;
    __syncthreads();
    int woff = 0;
    for (int i = 0; i < w; ++i) woff += wtot[i];
    int exc0 = woff + incl - s;
    binExc[2 * t] = exc0;
    binExc[2 * t + 1] = exc0 + c0;
    // One global reservation per non-empty bin (no dependence on binExc).
    for (int b = t; b < NBINS; b += 256) {
        int c = binCnt[b];
        if (c > 0) binG[b] = binPtr[b] + atomicAdd(&bucketFill[b], c);
    }
    __syncthreads();

    // Scatter records into LDS at bin-sorted positions.
#pragma unroll AEPT
    for (int k = 0; k < AEPT; ++k) {
        int i = t + k * 256;
        if (i < n) {
            int b = r_[k] >> 8;
            int slot = binExc[b] + atomicAdd(&binCur[b], 1);
            buf[slot] = make_uint2((unsigned)r_[k], pk_[k]);
        }
    }
    __syncthreads();

    // Coalesced copy-out: consecutive p within a run -> consecutive global dst.
    for (int p = t; p < n; p += 256) {
        uint2 rec = buf[p];
        int b = (int)(rec.x >> 8);
        int dst = binG[b] + (p - binExc[b]);
        records[dst] = rec;
    }
}

// ---------- phase B: per-bin row_ptr derivation + scatter to exact CSR slots ----------
// R11: 512 threads (12 waves/CU vs 6 -- was 1.5 WG/CU TLP-starved) and
// wave-shfl scan (3 barriers vs 16).
__global__ void __launch_bounds__(512) build_phaseB(const int* __restrict__ binPtr,
                                                    const uint2* __restrict__ records,
                                                    unsigned* __restrict__ s_edges,
                                                    int* __restrict__ row_ptr) {
    __shared__ int lcnt[ABINROWS];
    __shared__ int lrp[ABINROWS];
    __shared__ int lfill[ABINROWS];
    __shared__ int wtot[4];
    int b = blockIdx.x;
    int t = threadIdx.x;
    int lane = t & 63, w = t >> 6;
    int r0 = b * ABINROWS;
    int r1 = r0 + ABINROWS; if (r1 > N_NODES) r1 = N_NODES;
    int nr = r1 - r0;
    int beg = binPtr[b];
    int end = binPtr[b + 1];

    if (t < ABINROWS) { lcnt[t] = 0; lfill[t] = 0; }
    __syncthreads();
    // Pass 1: per-row histogram.
    for (int i = beg + t; i < end; i += 512) {
        atomicAdd(&lcnt[(int)records[i].x - r0], 1);
    }
    __syncthreads();
    // Wave-scan of 256 entries: waves 0..3 each scan 64 contiguous entries.
    int c = 0, incl = 0;
    if (t < ABINROWS) {
        c = lcnt[t];
        incl = wave_incl_scan(c, lane);
        if (lane == 63) wtot[w] = incl;
    }
    __syncthreads();
    if (t < ABINROWS) {
        int woff = 0;
        for (int i = 0; i < w; ++i) woff += wtot[i];
        lrp[t] = beg + woff + incl - c;   // exclusive prefix + bin base
        if (t < nr) row_ptr[r0 + t] = lrp[t];
    }
    if (t == 0) row_ptr[r0 + nr] = end;
    __syncthreads();
    // Pass 2: scatter (records re-read is L2-resident).
    for (int i = beg + t; i < end; i += 512) {
        uint2 rec = records[i];
        int lr = (int)rec.x - r0;
        int lp = atomicAdd(&lfill[lr], 1);
        s_edges[lrp[lr] + lp] = rec.y;
    }
}

// ---------- emb -> bf16 mirror (pure stream: nt both sides) ----------
__global__ void emb_to_bf16(const float* __restrict__ emb, unsigned short* __restrict__ mirror) {
    int t = blockIdx.x * blockDim.x + threadIdx.x;   // [0, N_NODES*16)
    if (t >= N_NODES * 16) return;
    f32x4 v = __builtin_nontemporal_load((const f32x4*)emb + t);
    u16x4 o;
    o.x = f32_to_bf16_rtn(v.x); o.y = f32_to_bf16_rtn(v.y);
    o.z = f32_to_bf16_rtn(v.z); o.w = f32_to_bf16_rtn(v.w);
    __builtin_nontemporal_store(o, (u16x4*)mirror + t);
}

// ---------- SpMM gather core, bf16 source: one wave per destination node ----------
// 4 groups x 16 lanes; lane j of a group owns bf16x4 chunk j of the 64-dim row.
// Edge words staged via ONE coalesced per-lane load (nt: no reuse), distributed
// with __shfl. Mirror gathers use normal cached loads (the only data with reuse).
// Control flow is wave-uniform (shfl from inactive lanes is undefined on CDNA).

__device__ __forceinline__ void gacc(float4& acc, unsigned p, int j,
                                     const unsigned short* __restrict__ srcMirror) {
    float v = __half2float(__ushort_as_half((unsigned short)(p & 0x7FFFu)));
    ushort4 m = *(const ushort4*)(srcMirror + (size_t)(p >> 15) * 64 + j * 4);
    acc.x += v * bf16_to_f32(m.x);
    acc.y += v * bf16_to_f32(m.y);
    acc.z += v * bf16_to_f32(m.z);
    acc.w += v * bf16_to_f32(m.w);
}

__device__ __forceinline__ float4 spmm_row_core(int beg, int end, int g, int j, int lane,
                                                const unsigned* __restrict__ s_edges,
                                                const unsigned short* __restrict__ srcMirror) {
    int deg = end - beg;                  // wave-uniform
    unsigned ew = (lane < deg) ? __builtin_nontemporal_load(s_edges + beg + lane) : 0u;
    float4 acc = make_float4(0.f, 0.f, 0.f, 0.f);
    int nfull = deg < 64 ? deg : 64;      // wave-uniform
    for (int kb = 0; kb < nfull; kb += 16) {
        int k0 = kb + g, k1 = kb + g + 4, k2 = kb + g + 8, k3 = kb + g + 12;
        unsigned p0 = __shfl(ew, k0);
        unsigned p1 = __shfl(ew, k1);
        unsigned p2 = __shfl(ew, k2);
        unsigned p3 = __shfl(ew, k3);
        if (k0 < nfull) gacc(acc, p0, j, srcMirror);
        if (k1 < nfull) gacc(acc, p1, j, srcMirror);
        if (k2 < nfull) gacc(acc, p2, j, srcMirror);
        if (k3 < nfull) gacc(acc, p3, j, srcMirror);
    }
    for (int e = beg + 64 + g; e < end; e += 4) {
        unsigned p = s_edges[e];
        gacc(acc, p, j, srcMirror);
    }
    acc.x += __shfl_xor(acc.x, 16); acc.y += __shfl_xor(acc.y, 16);
    acc.z += __shfl_xor(acc.z, 16); acc.w += __shfl_xor(acc.w, 16);
    acc.x += __shfl_xor(acc.x, 32); acc.y += __shfl_xor(acc.y, 32);
    acc.z += __shfl_xor(acc.z, 32); acc.w += __shfl_xor(acc.w, 32);
    return acc;
}

__global__ void __launch_bounds__(256) spmm_gather_bf16_mid(const int* __restrict__ row_ptr,
                                                            const unsigned* __restrict__ s_edges,
                                                            const unsigned short* __restrict__ srcMirror,
                                                            float* __restrict__ dstStacked,
                                                            unsigned short* __restrict__ dstMirror) {
    int wave = (blockIdx.x * blockDim.x + threadIdx.x) >> 6;
    if (wave >= N_NODES) return;
    int lane = threadIdx.x & 63;
    int g = lane >> 4, j = lane & 15;
    float4 acc = spmm_row_core(row_ptr[wave], row_ptr[wave + 1], g, j, lane, s_edges, srcMirror);
    if (lane < 16) {
        f32x4 vv = {acc.x, acc.y, acc.z, acc.w};
        __builtin_nontemporal_store(vv, (f32x4*)(dstStacked + (size_t)wave * 256 + j * 4));
        u16x4 o;
        o.x = f32_to_bf16_rtn(acc.x); o.y = f32_to_bf16_rtn(acc.y);
        o.z = f32_to_bf16_rtn(acc.z); o.w = f32_to_bf16_rtn(acc.w);
        __builtin_nontemporal_store(o, (u16x4*)(dstMirror + (size_t)wave * 64 + j * 4));
    }
}

// Last layer: fuse the 4-layer mean + layer-0 copy into the same dispatch.
__global__ void __launch_bounds__(256) spmm_gather_bf16_last(const int* __restrict__ row_ptr,
                                                             const unsigned* __restrict__ s_edges,
                                                             const unsigned short* __restrict__ srcMirror,
                                                             const float* __restrict__ emb,
                                                             float* __restrict__ stacked,
                                                             float* __restrict__ meanOut) {
    int wave = (blockIdx.x * blockDim.x + threadIdx.x) >> 6;
    if (wave >= N_NODES) return;
    int lane = threadIdx.x & 63;
    int g = lane >> 4, j = lane & 15;
    float4 acc = spmm_row_core(row_ptr[wave], row_ptr[wave + 1], g, j, lane, s_edges, srcMirror);
    if (lane < 16) {
        float* base = stacked + (size_t)wave * 256 + j * 4;
        f32x4 a  = __builtin_nontemporal_load((const f32x4*)(emb + (size_t)wave * 64 + j * 4));
        f32x4 b1 = __builtin_nontemporal_load((const f32x4*)(base + 64));
        f32x4 c2 = __builtin_nontemporal_load((const f32x4*)(base + 128));
        f32x4 d3 = {acc.x, acc.y, acc.z, acc.w};
        __builtin_nontemporal_store(a, (f32x4*)base);            // layer 0
        __builtin_nontemporal_store(d3, (f32x4*)(base + 192));   // layer 3
        f32x4 s;
        s.x = 0.25f * (a.x + b1.x + c2.x + d3.x);
        s.y = 0.25f * (a.y + b1.y + c2.y + d3.y);
        s.z = 0.25f * (a.z + b1.z + c2.z + d3.z);
        s.w = 0.25f * (a.w + b1.w + c2.w + d3.w);
        __builtin_nontemporal_store(s, (f32x4*)(meanOut + (size_t)wave * 64 + j * 4));
    }
}

// ---------- mean over 4 layers (f32 fallback path) ----------
__global__ void mean_layers(const float* __restrict__ emb,
                            float* __restrict__ stacked,
                            float* __restrict__ meanOut) {
    int t = blockIdx.x * blockDim.x + threadIdx.x;   // [0, N_NODES*16)
    if (t >= N_NODES * 16) return;
    int n = t >> 4;
    int j = t & 15;
    float4* base = (float4*)stacked + (size_t)n * 64;
    float4 a = ((const float4*)emb)[t];
    float4 b = base[16 + j];
    float4 c = base[32 + j];
    float4 d = base[48 + j];
    base[j] = a;
    float4 s;
    s.x = 0.25f * (a.x + b.x + c.x + d.x);
    s.y = 0.25f * (a.y + b.y + c.y + d.y);
    s.z = 0.25f * (a.z + b.z + c.z + d.z);
    s.w = 0.25f * (a.w + b.w + c.w + d.w);
    ((float4*)meanOut)[t] = s;
}

// ---------- mid fallback: fp32 CSR gather ----------

__global__ void scatter_edges_int2(const int* __restrict__ rows, const int* __restrict__ cols,
                                   const float* __restrict__ vals,
                                   const int* __restrict__ row_ptr, int* __restrict__ fill,
                                   int2* __restrict__ s_colval) {
    int e = blockIdx.x * blockDim.x + threadIdx.x;
    if (e >= N_EDGES) return;
    int r = rows[e];
    int pos = row_ptr[r] + atomicAdd(&fill[r], 1);
    int2 p; p.x = cols[e]; p.y = __float_as_int(vals[e]);
    s_colval[pos] = p;
}

__global__ void __launch_bounds__(256) spmm_gather_f32(const int* __restrict__ row_ptr,
                                                       const int2* __restrict__ s_colval,
                                                       const float* __restrict__ src, int srcStride,
                                                       float* __restrict__ dst) {
    int wave = (blockIdx.x * blockDim.x + threadIdx.x) >> 6;
    if (wave >= N_NODES) return;
    int lane = threadIdx.x & 63;
    int g = lane >> 4, j = lane & 15;
    int beg = row_ptr[wave], end = row_ptr[wave + 1];
    float4 acc = make_float4(0.f, 0.f, 0.f, 0.f);
    int e = beg + g;
    for (; e + 4 < end; e += 8) {
        int2 p0 = s_colval[e], p1 = s_colval[e + 4];
        float v0 = __int_as_float(p0.y), v1 = __int_as_float(p1.y);
        float4 m0 = *(const float4*)(src + (size_t)p0.x * srcStride + j * 4);
        float4 m1 = *(const float4*)(src + (size_t)p1.x * srcStride + j * 4);
        acc.x += v0 * m0.x + v1 * m1.x; acc.y += v0 * m0.y + v1 * m1.y;
        acc.z += v0 * m0.z + v1 * m1.z; acc.w += v0 * m0.w + v1 * m1.w;
    }
    for (; e < end; e += 4) {
        int2 p = s_colval[e];
        float v = __int_as_float(p.y);
        float4 m = *(const float4*)(src + (size_t)p.x * srcStride + j * 4);
        acc.x += v * m.x; acc.y += v * m.y; acc.z += v * m.z; acc.w += v * m.w;
    }
    acc.x += __shfl_xor(acc.x, 16); acc.y += __shfl_xor(acc.y, 16);
    acc.z += __shfl_xor(acc.z, 16); acc.w += __shfl_xor(acc.w, 16);
    acc.x += __shfl_xor(acc.x, 32); acc.y += __shfl_xor(acc.y, 32);
    acc.z += __shfl_xor(acc.z, 32); acc.w += __shfl_xor(acc.w, 32);
    if (lane < 16)
        *(float4*)(dst + (size_t)wave * 256 + j * 4) = acc;
}

// ---------- last fallback: atomic scatter ----------

__global__ void init_stacked_full(const float* __restrict__ emb, float* __restrict__ stacked) {
    int t = blockIdx.x * blockDim.x + threadIdx.x;
    if (t >= N_NODES * 64) return;
    int n = t >> 6, j = t & 63;
    float4 v = (j < 16) ? ((const float4*)emb)[n * 16 + j] : make_float4(0.f, 0.f, 0.f, 0.f);
    ((float4*)stacked)[n * 64 + j] = v;
}

__global__ void spmm_atomic(const int* __restrict__ rows, const int* __restrict__ cols,
                            const float* __restrict__ vals, float* __restrict__ stacked,
                            int lprev) {
    int t = blockIdx.x * blockDim.x + threadIdx.x;
    int e = t >> 4, j = t & 15;
    if (e >= N_EDGES) return;
    int r = rows[e], c = cols[e];
    float v = vals[e];
    const float4* src = (const float4*)(stacked + (size_t)c * 256 + lprev * 64);
    float4 m = src[j];
    float* dst = stacked + (size_t)r * 256 + (lprev + 1) * 64 + j * 4;
    atomicAdd(dst + 0, v * m.x); atomicAdd(dst + 1, v * m.y);
    atomicAdd(dst + 2, v * m.z); atomicAdd(dst + 3, v * m.w);
}

__global__ void mean_layers_plain(const float* __restrict__ stacked, float* __restrict__ meanOut) {
    int t = blockIdx.x * blockDim.x + threadIdx.x;
    if (t >= N_NODES * 16) return;
    int n = t >> 4, j = t & 15;
    const float4* base = (const float4*)(stacked + (size_t)n * 256);
    float4 a = base[j], b = base[16 + j], c = base[32 + j], d = base[48 + j];
    float4 s;
    s.x = 0.25f * (a.x + b.x + c.x + d.x);
    s.y = 0.25f * (a.y + b.y + c.y + d.y);
    s.z = 0.25f * (a.z + b.z + c.z + d.z);
    s.w = 0.25f * (a.w + b.w + c.w + d.w);
    ((float4*)meanOut)[t] = s;
}

extern "C" void kernel_launch(void* const* d_in, const int* in_sizes, int n_in,
                              void* d_out, int out_size, void* d_ws, size_t ws_size,
                              hipStream_t stream) {
    const float* emb  = (const float*)d_in[0];
    const int*   rows = (const int*)d_in[1];
    const int*   cols = (const int*)d_in[2];
    const float* vals = (const float*)d_in[3];

    float* meanOut = (float*)d_out;
    float* stacked = (float*)d_out + (size_t)N_NODES * EMB_DIM;

    const size_t headInts = (size_t)(N_NODES * 2 + 1 + 2 * N_SCAN_BLOCKS);
    size_t need_bf16 = headInts * sizeof(int) + 64
                     + (size_t)N_EDGES * sizeof(unsigned)
                     + 2 * (size_t)N_NODES * EMB_DIM * sizeof(unsigned short);
    size_t need_f32  = headInts * sizeof(int) + 64 + (size_t)N_EDGES * sizeof(int2);

    if (ws_size >= need_bf16) {
        char* w = (char*)d_ws;
        int* counts    = (int*)w;  w += (size_t)N_NODES * sizeof(int);
        int* row_ptr   = (int*)w;  w += (size_t)(N_NODES + 1) * sizeof(int);
        int* blockSums = (int*)w;  w += (size_t)N_SCAN_BLOCKS * sizeof(int);
        int* blockOffs = (int*)w;  w += (size_t)N_SCAN_BLOCKS * sizeof(int);
        w = (char*)(((uintptr_t)w + 15) & ~(uintptr_t)15);
        unsigned* s_edges = (unsigned*)w;  w += (size_t)N_EDGES * sizeof(unsigned);
        unsigned short* mirrorA = (unsigned short*)w;  w += (size_t)N_NODES * EMB_DIM * sizeof(unsigned short);
        unsigned short* mirrorB = (unsigned short*)w;
        // Phase-A record staging aliases mirrorA+mirrorB (3.2M * 8B = 25.6 MB).
        // Mirrors are written only AFTER phaseB consumes records.
        uint2* records = (uint2*)mirrorA;
        // Bin-level arrays live in the (otherwise unused) counts region.
        int* binCounts  = counts;                 // NBINS
        int* bucketFill = counts + NBINS;         // NBINS
        int* binPtr     = counts + 2 * NBINS;     // NBINS+1

        hipMemsetAsync(counts, 0, (size_t)(2 * NBINS) * sizeof(int), stream);
        bin_count<<<NBCHUNKS, 256, 0, stream>>>(rows, binCounts);
        bin_scan<<<1, 512, 0, stream>>>(binCounts, binPtr);
        build_sortA<<<NCHUNKS, 256, 0, stream>>>(rows, cols, vals, binPtr, bucketFill, records);
        build_phaseB<<<NBINS, 512, 0, stream>>>(binPtr, records, s_edges, row_ptr);
        {
            int total = N_NODES * 16;
            int block = 256, grid = (total + block - 1) / block;
            emb_to_bf16<<<grid, block, 0, stream>>>(emb, mirrorA);
        }
        {
            long long threads = (long long)N_NODES * 64;
            int block = 256;
            int grid = (int)((threads + block - 1) / block);
            spmm_gather_bf16_mid<<<grid, block, 0, stream>>>(row_ptr, s_edges, mirrorA, stacked + 1 * 64, mirrorB);
            spmm_gather_bf16_mid<<<grid, block, 0, stream>>>(row_ptr, s_edges, mirrorB, stacked + 2 * 64, mirrorA);
            spmm_gather_bf16_last<<<grid, block, 0, stream>>>(row_ptr, s_edges, mirrorA, emb, stacked, meanOut);
        }
    } else if (ws_size >= need_f32) {
        char* w = (char*)d_ws;
        int* counts    = (int*)w;  w += (size_t)N_NODES * sizeof(int);
        int* row_ptr   = (int*)w;  w += (size_t)(N_NODES + 1) * sizeof(int);
        int* blockSums = (int*)w;  w += (size_t)N_SCAN_BLOCKS * sizeof(int);
        int* blockOffs = (int*)w;  w += (size_t)N_SCAN_BLOCKS * sizeof(int);
        w = (char*)(((uintptr_t)w + 15) & ~(uintptr_t)15);
        int2* s_colval = (int2*)w;

        hipMemsetAsync(counts, 0, (size_t)N_NODES * sizeof(int), stream);
        {
            int block = 256, grid = (N_EDGES + block - 1) / block;
            count_rows<<<grid, block, 0, stream>>>(rows, counts);
        }
        scan_phase1<<<N_SCAN_BLOCKS, SCAN_BLOCK, 0, stream>>>(counts, blockSums);
        scan_phase2<<<1, 256, 0, stream>>>(blockSums, blockOffs, row_ptr);
        scan_phase3<<<N_SCAN_BLOCKS, SCAN_BLOCK, 0, stream>>>(counts, blockOffs, row_ptr);
        hipMemsetAsync(counts, 0, (size_t)N_NODES * sizeof(int), stream);
        {
            int block = 256, grid = (N_EDGES + block - 1) / block;
            scatter_edges_int2<<<grid, block, 0, stream>>>(rows, cols, vals, row_ptr, counts, s_colval);
        }
        {
            long long threads = (long long)N_NODES * 64;
            int block = 256;
            int grid = (int)((threads + block - 1) / block);
            spmm_gather_f32<<<grid, block, 0, stream>>>(row_ptr, s_colval, emb, 64, stacked + 1 * 64);
            spmm_gather_f32<<<grid, block, 0, stream>>>(row_ptr, s_colval, stacked + 1 * 64, 256, stacked + 2 * 64);
            spmm_gather_f32<<<grid, block, 0, stream>>>(row_ptr, s_colval, stacked + 2 * 64, 256, stacked + 3 * 64);
        }
        {
            int total = N_NODES * 16;
            int block = 256, grid = (total + block - 1) / block;
            mean_layers<<<grid, block, 0, stream>>>(emb, stacked, meanOut);
        }
    } else {
        {
            int total = N_NODES * 64;
            int block = 256, grid = (total + block - 1) / block;
            init_stacked_full<<<grid, block, 0, stream>>>(emb, stacked);
        }
        {
            long long total = (long long)N_EDGES * 16;
            int block = 256, grid = (int)((total + block - 1) / block);
            for (int l = 0; l < N_LAYERS; ++l)
                spmm_atomic<<<grid, block, 0, stream>>>(rows, cols, vals, stacked, l);
        }
        {
            int total = N_NODES * 16;
            int block = 256, grid = (total + block - 1) / block;
            mean_layers_plain<<<grid, block, 0, stream>>>(stacked, meanOut);
        }
    }
}